// Round 5
// baseline (386.576 us; speedup 1.0000x reference)
//
#include <hip/hip_runtime.h>
#include <stdint.h>

// Problem constants
#define NB       64
#define FIN      12
#define HD       64
#define NHEADS   4
#define DHEAD    16
#define NLAYERS  3
#define ODIM     128
#define LN_EPS   1e-5f
#define BTOT     8192

#define LDB      72    // u16 stride for all fp16 LDS tiles (144 B rows, 16B-aligned)
#define NTH      256
#define NW       (NLAYERS * 4)
#define WFRAG    4096  // u16 per packed weight

typedef unsigned int       u32;
typedef unsigned short     u16;
typedef unsigned long long u64;
typedef _Float16           f16;

typedef f16   f16x8 __attribute__((ext_vector_type(8)));
typedef f16   h2    __attribute__((ext_vector_type(2)));
typedef float f32x4 __attribute__((ext_vector_type(4)));
union U128h { uint4 u; f16x8 v8; h2 v2[4]; };

#if __has_builtin(__builtin_amdgcn_exp2f)
  __device__ __forceinline__ float e2(float x) { return __builtin_amdgcn_exp2f(x); }
#else
  __device__ __forceinline__ float e2(float x) { return exp2f(x); }
#endif

// fp32 += fp16-pair dot (v_dot2_f32_f16)
__device__ __forceinline__ float fdot2h(h2 a, h2 b, float c) {
#if __has_builtin(__builtin_amdgcn_fdot2)
  return __builtin_amdgcn_fdot2(a, b, c, false);
#else
  return c + (float)a[0] * (float)b[0] + (float)a[1] * (float)b[1];
#endif
}

struct __align__(16) Smem {
  u16 Kh[NB * LDB];   // 9216  k fp16
  u16 Vh[NB * LDB];   // 9216  v fp16
  u16 Hb[NB * LDB];   // 9216  h fp16 (MFMA A source)
  u16 Qb[NB * LDB];   // 9216  q fp16 (scale pre-folded), then attention output o
  union {             //  512  disjoint lifetimes
    u64 mask[NB];
    struct { float pool[HD]; float y1[HD]; } hp;
  } u;
};                    // 37376 B -> 4 blocks/CU

// ---------------- prep: pack 12 weights into fp16 B-fragment order + adjacency masks
// frag f (0..511): lane=f&63, kh=(f>>6)&1, nt=f>>7
// elem j: B[n=nt*16+(lane&15)][k=kh*32+((lane>>4)&3)*8+j]  (src k-major W[k][n])
extern "C" __global__ void __launch_bounds__(256)
prep_pack(const float* __restrict__ Wq, const float* __restrict__ Wk,
          const float* __restrict__ Wv, const float* __restrict__ Wo,
          const int* __restrict__ adj, u16* __restrict__ wsW, u64* __restrict__ wsM) {
  const int w = blockIdx.x;
  if (w < NW) {
    const int l = w >> 2, ty = w & 3;
    const float* src = (ty == 0 ? Wq : ty == 1 ? Wk : ty == 2 ? Wv : Wo) + l * HD * HD;
    const float sc = (ty == 0) ? (0.25f * 1.44269504f) : 1.0f;  // fold softmax*log2e into Wq
    u16* dst = wsW + w * WFRAG;
    for (int f = threadIdx.x; f < 512; f += 256) {
      const int lane = f & 63, kh = (f >> 6) & 1, nt = f >> 7;
      const int n  = nt * 16 + (lane & 15);
      const int k0 = kh * 32 + ((lane >> 4) & 3) * 8;
      u16 tmp[8];
      #pragma unroll
      for (int j = 0; j < 8; ++j) {
        f16 hv = (f16)(src[(k0 + j) * HD + n] * sc);
        tmp[j] = *(u16*)&hv;
      }
      *(uint4*)(dst + f * 8) = *(const uint4*)tmp;
    }
  } else {
    const int t = threadIdx.x;
    if (t < NB) {
      u64 mm = 0ull;
      for (int j = 0; j < NB; ++j)
        if (adj[t * NB + j] != 0) mm |= (1ull << j);
      wsM[t] = mm;
    }
  }
}

// wave: rows [m0,m0+16) x 64 cols of A(64x64) @ W(64x64), fp16 MFMA.
// C layout: row = m0 + (lane>>4)*4 + r, col = nt*16 + (lane&15).
__device__ __forceinline__ void mm16x64h(U128h a0, U128h a1,
                                         const u16* __restrict__ wf,
                                         int lane, f32x4 acc[4]) {
  #pragma unroll
  for (int nt = 0; nt < 4; ++nt) {
    U128h b0, b1;
    b0.u = *(const uint4*)(wf + ((nt * 2 + 0) * 64 + lane) * 8);
    b1.u = *(const uint4*)(wf + ((nt * 2 + 1) * 64 + lane) * 8);
    acc[nt] = __builtin_amdgcn_mfma_f32_16x16x32_f16(a0.v8, b0.v8, acc[nt], 0, 0, 0);
    acc[nt] = __builtin_amdgcn_mfma_f32_16x16x32_f16(a1.v8, b1.v8, acc[nt], 0, 0, 0);
  }
}

// one attention edge: s = q.k (fdot2 chains), p = exp2(s), o += p*v (pk_fma_f16)
__device__ __forceinline__ void attn_edge(const U128h& q0, const U128h& q1,
                                          U128h k0, U128h k1, U128h v0, U128h v1,
                                          float& sum, h2* __restrict__ o) {
  float d0 = fdot2h(q0.v2[0], k0.v2[0], 0.0f);
  d0 = fdot2h(q0.v2[1], k0.v2[1], d0);
  d0 = fdot2h(q0.v2[2], k0.v2[2], d0);
  d0 = fdot2h(q0.v2[3], k0.v2[3], d0);
  float d1 = fdot2h(q1.v2[0], k1.v2[0], 0.0f);
  d1 = fdot2h(q1.v2[1], k1.v2[1], d1);
  d1 = fdot2h(q1.v2[2], k1.v2[2], d1);
  d1 = fdot2h(q1.v2[3], k1.v2[3], d1);
  const float p = e2(d0 + d1);
  sum += p;
  const f16 ph = (f16)p;
  const h2 p2 = {ph, ph};
  o[0] += p2 * v0.v2[0]; o[1] += p2 * v0.v2[1];
  o[2] += p2 * v0.v2[2]; o[3] += p2 * v0.v2[3];
  o[4] += p2 * v1.v2[0]; o[5] += p2 * v1.v2[1];
  o[6] += p2 * v1.v2[2]; o[7] += p2 * v1.v2[3];
}

extern "C" __global__ void __launch_bounds__(NTH, 4)
gnn_fused(const float* __restrict__ x, const float* __restrict__ W_in,
          const float* __restrict__ b_in, const u16* __restrict__ wsW,
          const u64* __restrict__ wsM, const float* __restrict__ bo,
          const float* __restrict__ ln_g, const float* __restrict__ ln_b,
          const float* __restrict__ Wp1, const float* __restrict__ bp1,
          const float* __restrict__ Wp2, const float* __restrict__ bp2,
          float* __restrict__ out) {
  __shared__ Smem s;
  const int t    = threadIdx.x;
  const int lane = t & 63;
  const int wv   = t >> 6;
  const int m0   = wv * 16;
  const int eg   = (int)blockIdx.x;
  const int m    = lane & 15, q = lane >> 4;

  f16* __restrict__ Kh = (f16*)s.Kh;
  f16* __restrict__ Vh = (f16*)s.Vh;
  f16* __restrict__ Hh = (f16*)s.Hb;
  f16* __restrict__ Qh = (f16*)s.Qb;

  // ---------------- phase 0: masks from prep (no per-block rebuild)
  if (t < NB) s.u.mask[t] = wsM[t];

  // ---------------- input projection in C-fragment layout (fp32), x direct from global
  float hr[4][4];   // [nt][r]: cell (row = m0+q*4+r, col = nt*16+m)
  {
    const float* xb = x + eg * NB * FIN;
    float xr[4][FIN];
    #pragma unroll
    for (int r = 0; r < 4; ++r) {
      const float4* xp = (const float4*)(xb + (m0 + q * 4 + r) * FIN);
      const float4 a = xp[0], b4 = xp[1], c4 = xp[2];
      xr[r][0] = a.x;  xr[r][1] = a.y;  xr[r][2]  = a.z;  xr[r][3]  = a.w;
      xr[r][4] = b4.x; xr[r][5] = b4.y; xr[r][6]  = b4.z; xr[r][7]  = b4.w;
      xr[r][8] = c4.x; xr[r][9] = c4.y; xr[r][10] = c4.z; xr[r][11] = c4.w;
    }
    #pragma unroll
    for (int nt = 0; nt < 4; ++nt)
      #pragma unroll
      for (int r = 0; r < 4; ++r) hr[nt][r] = 0.0f;
    #pragma unroll 4
    for (int k = 0; k < FIN; ++k) {
      float w[4];
      #pragma unroll
      for (int nt = 0; nt < 4; ++nt) w[nt] = W_in[k * HD + nt * 16 + m];
      #pragma unroll
      for (int nt = 0; nt < 4; ++nt)
        #pragma unroll
        for (int r = 0; r < 4; ++r) hr[nt][r] = fmaf(xr[r][k], w[nt], hr[nt][r]);
    }
    #pragma unroll
    for (int nt = 0; nt < 4; ++nt) {
      const float bn = b_in[nt * 16 + m];
      #pragma unroll
      for (int r = 0; r < 4; ++r) {
        hr[nt][r] += bn;
        Hh[(m0 + q * 4 + r) * LDB + nt * 16 + m] = (f16)hr[nt][r];
      }
    }
  }
  __syncthreads();

  // ---------------- transformer layers
  for (int l = 0; l < NLAYERS; ++l) {
    const u16* wl = wsW + (l * 4) * WFRAG;

    // fused q/k/v projections (shared A-fragments; fp16 writebacks, 1-op cvt)
    {
      U128h a0, a1;
      const u16* ar = &s.Hb[(m0 + m) * LDB + q * 8];
      a0.u = *(const uint4*)ar;
      a1.u = *(const uint4*)(ar + 32);

      f32x4 aq[4] = {{0,0,0,0},{0,0,0,0},{0,0,0,0},{0,0,0,0}};
      mm16x64h(a0, a1, wl + 0 * WFRAG, lane, aq);
      #pragma unroll
      for (int nt = 0; nt < 4; ++nt)
        #pragma unroll
        for (int r = 0; r < 4; ++r)
          Qh[(m0 + q * 4 + r) * LDB + nt * 16 + m] = (f16)aq[nt][r];

      f32x4 ak[4] = {{0,0,0,0},{0,0,0,0},{0,0,0,0},{0,0,0,0}};
      mm16x64h(a0, a1, wl + 1 * WFRAG, lane, ak);
      #pragma unroll
      for (int nt = 0; nt < 4; ++nt)
        #pragma unroll
        for (int r = 0; r < 4; ++r)
          Kh[(m0 + q * 4 + r) * LDB + nt * 16 + m] = (f16)ak[nt][r];

      f32x4 av[4] = {{0,0,0,0},{0,0,0,0},{0,0,0,0},{0,0,0,0}};
      mm16x64h(a0, a1, wl + 2 * WFRAG, lane, av);
      #pragma unroll
      for (int nt = 0; nt < 4; ++nt)
        #pragma unroll
        for (int r = 0; r < 4; ++r)
          Vh[(m0 + q * 4 + r) * LDB + nt * 16 + m] = (f16)av[nt][r];
    }
    __syncthreads();

    // sparse masked attention; fp16 K/V, fdot2 + pk_fma, ping-pong prefetch
    {
      const int hh = wv, i = lane;
      const uint4* qp = (const uint4*)&s.Qb[i * LDB + hh * DHEAD];
      U128h q0, q1;
      q0.u = qp[0]; q1.u = qp[1];     // scale already folded into Wq

      u64 mk = s.u.mask[i];
      float sum = 0.0f;
      h2 o2[8];
      #pragma unroll
      for (int c = 0; c < 8; ++c) o2[c] = (h2){(f16)0.0f, (f16)0.0f};

      int j = (int)__builtin_ctzll(mk); mk &= mk - 1;
      const uint4* kp = (const uint4*)&s.Kh[j * LDB + hh * DHEAD];
      const uint4* vp = (const uint4*)&s.Vh[j * LDB + hh * DHEAD];
      U128h k0, k1, v0, v1;
      k0.u = kp[0]; k1.u = kp[1]; v0.u = vp[0]; v1.u = vp[1];

      for (;;) {
        if (!mk) { attn_edge(q0, q1, k0, k1, v0, v1, sum, o2); break; }
        j = (int)__builtin_ctzll(mk); mk &= mk - 1;
        const uint4* kp2 = (const uint4*)&s.Kh[j * LDB + hh * DHEAD];
        const uint4* vp2 = (const uint4*)&s.Vh[j * LDB + hh * DHEAD];
        U128h k0b, k1b, v0b, v1b;
        k0b.u = kp2[0]; k1b.u = kp2[1]; v0b.u = vp2[0]; v1b.u = vp2[1];
        attn_edge(q0, q1, k0, k1, v0, v1, sum, o2);
        if (!mk) { attn_edge(q0, q1, k0b, k1b, v0b, v1b, sum, o2); break; }
        j = (int)__builtin_ctzll(mk); mk &= mk - 1;
        kp = (const uint4*)&s.Kh[j * LDB + hh * DHEAD];
        vp = (const uint4*)&s.Vh[j * LDB + hh * DHEAD];
        k0.u = kp[0]; k1.u = kp[1]; v0.u = vp[0]; v1.u = vp[1];
        attn_edge(q0, q1, k0b, k1b, v0b, v1b, sum, o2);
      }

      const float rinv = 1.0f / sum;
      const f16 rh = (f16)rinv;
      const h2 r2 = {rh, rh};
      U128h w0, w1;
      #pragma unroll
      for (int c = 0; c < 4; ++c) w0.v2[c] = o2[c] * r2;
      #pragma unroll
      for (int c = 0; c < 4; ++c) w1.v2[c] = o2[c + 4] * r2;
      uint4* op = (uint4*)&s.Qb[i * LDB + hh * DHEAD];
      op[0] = w0.u; op[1] = w1.u;     // fp16 out, directly MFMA-A-consumable
    }
    __syncthreads();

    // u = h + o @ Wo + bo (fp32 regs), LN (regs + shfl), h -> hr (+Hb fp16)
    {
      U128h a0, a1;
      const u16* ar = &s.Qb[(m0 + m) * LDB + q * 8];
      a0.u = *(const uint4*)ar;
      a1.u = *(const uint4*)(ar + 32);
      f32x4 ao[4] = {{0,0,0,0},{0,0,0,0},{0,0,0,0},{0,0,0,0}};
      mm16x64h(a0, a1, wl + 3 * WFRAG, lane, ao);

      float uu[4][4];
      #pragma unroll
      for (int nt = 0; nt < 4; ++nt) {
        const float bn = bo[l * HD + nt * 16 + m];
        #pragma unroll
        for (int r = 0; r < 4; ++r)
          uu[nt][r] = hr[nt][r] + ao[nt][r] + bn;
      }
      float s1[4], s2[4];
      #pragma unroll
      for (int r = 0; r < 4; ++r) {
        s1[r] = ((uu[0][r] + uu[1][r]) + (uu[2][r] + uu[3][r]));
        s2[r] = ((uu[0][r] * uu[0][r] + uu[1][r] * uu[1][r]) +
                 (uu[2][r] * uu[2][r] + uu[3][r] * uu[3][r]));
      }
      #pragma unroll
      for (int d = 1; d < 16; d <<= 1) {
        #pragma unroll
        for (int r = 0; r < 4; ++r) {
          s1[r] += __shfl_xor(s1[r], d, 64);
          s2[r] += __shfl_xor(s2[r], d, 64);
        }
      }
      float mu[4], rs[4];
      #pragma unroll
      for (int r = 0; r < 4; ++r) {
        mu[r] = s1[r] * (1.0f / 64.0f);
        const float var = s2[r] * (1.0f / 64.0f) - mu[r] * mu[r];
        rs[r] = rsqrtf(var + LN_EPS);
      }
      const bool wb = (l + 1 < NLAYERS);
      #pragma unroll
      for (int nt = 0; nt < 4; ++nt) {
        const float gv = ln_g[l * HD + nt * 16 + m];
        const float bv = ln_b[l * HD + nt * 16 + m];
        #pragma unroll
        for (int r = 0; r < 4; ++r) {
          hr[nt][r] = (uu[nt][r] - mu[r]) * rs[r] * gv + bv;
          if (wb) Hh[(m0 + q * 4 + r) * LDB + nt * 16 + m] = (f16)hr[nt][r];
        }
      }
    }
    __syncthreads();
  }

  // ---------------- head: pool (registers + LDS atomics) -> MLP
  if (t < HD) s.u.hp.pool[t] = 0.0f;
  __syncthreads();
  {
    float cs[4];
    #pragma unroll
    for (int nt = 0; nt < 4; ++nt) {
      cs[nt] = ((hr[nt][0] + hr[nt][1]) + (hr[nt][2] + hr[nt][3])) * (1.0f / 64.0f);
      cs[nt] += __shfl_xor(cs[nt], 16, 64);
      cs[nt] += __shfl_xor(cs[nt], 32, 64);
    }
    if (lane < 16) {
      #pragma unroll
      for (int nt = 0; nt < 4; ++nt)
        atomicAdd(&s.u.hp.pool[nt * 16 + lane], cs[nt]);
    }
  }
  __syncthreads();
  if (t < HD) {
    float acc = bp1[t];
    #pragma unroll 8
    for (int k = 0; k < HD; ++k) acc = fmaf(s.u.hp.pool[k], Wp1[k * HD + t], acc);
    s.u.hp.y1[t] = fmaxf(acc, 0.0f);
  }
  __syncthreads();
  if (t < ODIM) {
    float acc = bp2[t];
    #pragma unroll 8
    for (int c = 0; c < HD; ++c) acc = fmaf(s.u.hp.y1[c], Wp2[c * ODIM + t], acc);
    out[eg * ODIM + t] = acc;
  }
}

extern "C" void kernel_launch(void* const* d_in, const int* in_sizes, int n_in,
                              void* d_out, int out_size, void* d_ws, size_t ws_size,
                              hipStream_t stream) {
  const float* x    = (const float*)d_in[0];
  const int*   adj  = (const int*)d_in[1];
  const float* W_in = (const float*)d_in[2];
  const float* b_in = (const float*)d_in[3];
  const float* Wq   = (const float*)d_in[4];
  const float* Wk   = (const float*)d_in[5];
  const float* Wv   = (const float*)d_in[6];
  const float* Wo   = (const float*)d_in[7];
  const float* bo   = (const float*)d_in[8];
  const float* lng  = (const float*)d_in[9];
  const float* lnb  = (const float*)d_in[10];
  const float* Wp1  = (const float*)d_in[11];
  const float* bp1  = (const float*)d_in[12];
  const float* Wp2  = (const float*)d_in[13];
  const float* bp2  = (const float*)d_in[14];
  float* outp = (float*)d_out;
  u16*   wsW  = (u16*)d_ws;                      // 12 * 4096 u16 = 98304 B
  u64*   wsM  = (u64*)((char*)d_ws + NW * WFRAG * sizeof(u16));  // + 512 B

  hipLaunchKernelGGL(prep_pack, dim3(NW + 1), dim3(256), 0, stream,
                     Wq, Wk, Wv, Wo, adj, wsW, wsM);
  hipLaunchKernelGGL(gnn_fused, dim3(BTOT), dim3(NTH), 0, stream,
                     x, W_in, b_in, wsW, wsM, bo, lng, lnb,
                     Wp1, bp1, Wp2, bp2, outp);
}

// Round 6
// 322.078 us; speedup vs baseline: 1.2003x; 1.2003x over previous
//
#include <hip/hip_runtime.h>
#include <stdint.h>

// Problem constants
#define NB       64
#define FIN      12
#define HD       64
#define NHEADS   4
#define DHEAD    16
#define NLAYERS  3
#define ODIM     128
#define LN_EPS   1e-5f
#define BTOT     8192

#define LDB      72    // u16 stride for all fp16 LDS tiles (144 B rows, 16B-aligned)
#define NTH      256
#define NW       (NLAYERS * 4)
#define WFRAG    4096  // u16 per packed weight

typedef unsigned int       u32;
typedef unsigned short     u16;
typedef unsigned long long u64;
typedef _Float16           f16;

typedef f16   f16x8 __attribute__((ext_vector_type(8)));
typedef f16   h2    __attribute__((ext_vector_type(2)));
typedef float f32x4 __attribute__((ext_vector_type(4)));
union U128h { uint4 u; f16x8 v8; h2 v2[4]; };

#if __has_builtin(__builtin_amdgcn_exp2f)
  __device__ __forceinline__ float e2(float x) { return __builtin_amdgcn_exp2f(x); }
#else
  __device__ __forceinline__ float e2(float x) { return exp2f(x); }
#endif

// fp32 += fp16-pair dot (v_dot2_f32_f16)
__device__ __forceinline__ float fdot2h(h2 a, h2 b, float c) {
#if __has_builtin(__builtin_amdgcn_fdot2)
  return __builtin_amdgcn_fdot2(a, b, c, false);
#else
  return c + (float)a[0] * (float)b[0] + (float)a[1] * (float)b[1];
#endif
}

struct __align__(16) Smem {
  u16 Kh[NB * LDB];   // 9216  k fp16 (float x-staging scratch in phase 0: 768 floats)
  u16 Vh[NB * LDB];   // 9216  v fp16
  u16 Hb[NB * LDB];   // 9216  h fp16 (MFMA A source)
  u16 Qb[NB * LDB];   // 9216  q fp16 (scale pre-folded), then attention output o
  union {             //  512  disjoint lifetimes
    u64 mask[NB];
    struct { float pool[HD]; float y1[HD]; } hp;
  } u;
};                    // 37376 B -> 4 blocks/CU

// ---------------- prep: pack 12 weights into fp16 B-fragment order + adjacency masks
// frag f (0..511): lane=f&63, kh=(f>>6)&1, nt=f>>7
// elem j: B[n=nt*16+(lane&15)][k=kh*32+((lane>>4)&3)*8+j]  (src k-major W[k][n])
extern "C" __global__ void __launch_bounds__(256)
prep_pack(const float* __restrict__ Wq, const float* __restrict__ Wk,
          const float* __restrict__ Wv, const float* __restrict__ Wo,
          const int* __restrict__ adj, u16* __restrict__ wsW, u64* __restrict__ wsM) {
  const int w = blockIdx.x;
  if (w < NW) {
    const int l = w >> 2, ty = w & 3;
    const float* src = (ty == 0 ? Wq : ty == 1 ? Wk : ty == 2 ? Wv : Wo) + l * HD * HD;
    const float sc = (ty == 0) ? (0.25f * 1.44269504f) : 1.0f;  // fold softmax*log2e into Wq
    u16* dst = wsW + w * WFRAG;
    for (int f = threadIdx.x; f < 512; f += 256) {
      const int lane = f & 63, kh = (f >> 6) & 1, nt = f >> 7;
      const int n  = nt * 16 + (lane & 15);
      const int k0 = kh * 32 + ((lane >> 4) & 3) * 8;
      u16 tmp[8];
      #pragma unroll
      for (int j = 0; j < 8; ++j) {
        f16 hv = (f16)(src[(k0 + j) * HD + n] * sc);
        tmp[j] = *(u16*)&hv;
      }
      *(uint4*)(dst + f * 8) = *(const uint4*)tmp;
    }
  } else {
    const int t = threadIdx.x;
    if (t < NB) {
      u64 mm = 0ull;
      for (int j = 0; j < NB; ++j)
        if (adj[t * NB + j] != 0) mm |= (1ull << j);
      wsM[t] = mm;
    }
  }
}

// wave: rows [m0,m0+16) x 64 cols of A(64x64) @ W(64x64), fp16 MFMA.
// C layout: row = m0 + (lane>>4)*4 + r, col = nt*16 + (lane&15).
__device__ __forceinline__ void mm16x64h(U128h a0, U128h a1,
                                         const u16* __restrict__ wf,
                                         int lane, f32x4 acc[4]) {
  #pragma unroll
  for (int nt = 0; nt < 4; ++nt) {
    U128h b0, b1;
    b0.u = *(const uint4*)(wf + ((nt * 2 + 0) * 64 + lane) * 8);
    b1.u = *(const uint4*)(wf + ((nt * 2 + 1) * 64 + lane) * 8);
    acc[nt] = __builtin_amdgcn_mfma_f32_16x16x32_f16(a0.v8, b0.v8, acc[nt], 0, 0, 0);
    acc[nt] = __builtin_amdgcn_mfma_f32_16x16x32_f16(a1.v8, b1.v8, acc[nt], 0, 0, 0);
  }
}

// one attention edge: s = q.k (fdot2 chains), p = exp2(s), o += p*v (pk_fma_f16)
__device__ __forceinline__ void attn_edge(const U128h& q0, const U128h& q1,
                                          U128h k0, U128h k1, U128h v0, U128h v1,
                                          float& sum, h2* __restrict__ o) {
  float d0 = fdot2h(q0.v2[0], k0.v2[0], 0.0f);
  d0 = fdot2h(q0.v2[1], k0.v2[1], d0);
  d0 = fdot2h(q0.v2[2], k0.v2[2], d0);
  d0 = fdot2h(q0.v2[3], k0.v2[3], d0);
  float d1 = fdot2h(q1.v2[0], k1.v2[0], 0.0f);
  d1 = fdot2h(q1.v2[1], k1.v2[1], d1);
  d1 = fdot2h(q1.v2[2], k1.v2[2], d1);
  d1 = fdot2h(q1.v2[3], k1.v2[3], d1);
  const float p = e2(d0 + d1);
  sum += p;
  const f16 ph = (f16)p;
  const h2 p2 = {ph, ph};
  o[0] += p2 * v0.v2[0]; o[1] += p2 * v0.v2[1];
  o[2] += p2 * v0.v2[2]; o[3] += p2 * v0.v2[3];
  o[4] += p2 * v1.v2[0]; o[5] += p2 * v1.v2[1];
  o[6] += p2 * v1.v2[2]; o[7] += p2 * v1.v2[3];
}

extern "C" __global__ void __launch_bounds__(NTH, 4)
gnn_fused(const float* __restrict__ x, const float* __restrict__ W_in,
          const float* __restrict__ b_in, const u16* __restrict__ wsW,
          const u64* __restrict__ wsM, const float* __restrict__ bo,
          const float* __restrict__ ln_g, const float* __restrict__ ln_b,
          const float* __restrict__ Wp1, const float* __restrict__ bp1,
          const float* __restrict__ Wp2, const float* __restrict__ bp2,
          float* __restrict__ out) {
  __shared__ Smem s;
  const int t    = threadIdx.x;
  const int lane = t & 63;
  const int wv   = t >> 6;
  const int m0   = wv * 16;
  const int eg   = (int)blockIdx.x;
  const int m    = lane & 15, q = lane >> 4;

  f16* __restrict__ Kh = (f16*)s.Kh;
  f16* __restrict__ Vh = (f16*)s.Vh;
  f16* __restrict__ Hh = (f16*)s.Hb;
  f16* __restrict__ Qh = (f16*)s.Qb;

  // ---------------- phase 0: masks from prep + x -> LDS staging (Kh region as floats)
  if (t < NB) s.u.mask[t] = wsM[t];
  if (t < (NB * FIN) / 4)
    ((float4*)s.Kh)[t] = ((const float4*)(x + eg * NB * FIN))[t];
  __syncthreads();

  // ---------------- input projection in C-fragment layout (fp32); x from LDS
  // (LDS dynamic indexing is fine; a register array here would spill to scratch)
  float hr[4][4];   // [nt][r]: cell (row = m0+q*4+r, col = nt*16+m)
  {
    const float* xs = (const float*)s.Kh;
    #pragma unroll
    for (int nt = 0; nt < 4; ++nt)
      #pragma unroll
      for (int r = 0; r < 4; ++r) hr[nt][r] = 0.0f;
    #pragma unroll 4
    for (int k = 0; k < FIN; ++k) {
      float w[4], xv[4];
      #pragma unroll
      for (int nt = 0; nt < 4; ++nt) w[nt] = W_in[k * HD + nt * 16 + m];
      #pragma unroll
      for (int r = 0; r < 4; ++r) xv[r] = xs[(m0 + q * 4 + r) * FIN + k];
      #pragma unroll
      for (int nt = 0; nt < 4; ++nt)
        #pragma unroll
        for (int r = 0; r < 4; ++r) hr[nt][r] = fmaf(xv[r], w[nt], hr[nt][r]);
    }
    #pragma unroll
    for (int nt = 0; nt < 4; ++nt) {
      const float bn = b_in[nt * 16 + m];
      #pragma unroll
      for (int r = 0; r < 4; ++r) {
        hr[nt][r] += bn;
        Hh[(m0 + q * 4 + r) * LDB + nt * 16 + m] = (f16)hr[nt][r];
      }
    }
  }
  __syncthreads();

  // ---------------- transformer layers
  for (int l = 0; l < NLAYERS; ++l) {
    const u16* wl = wsW + (l * 4) * WFRAG;

    // fused q/k/v projections (shared A-fragments; fp16 writebacks, 1-op cvt)
    {
      U128h a0, a1;
      const u16* ar = &s.Hb[(m0 + m) * LDB + q * 8];
      a0.u = *(const uint4*)ar;
      a1.u = *(const uint4*)(ar + 32);

      f32x4 aq[4] = {{0,0,0,0},{0,0,0,0},{0,0,0,0},{0,0,0,0}};
      mm16x64h(a0, a1, wl + 0 * WFRAG, lane, aq);
      #pragma unroll
      for (int nt = 0; nt < 4; ++nt)
        #pragma unroll
        for (int r = 0; r < 4; ++r)
          Qh[(m0 + q * 4 + r) * LDB + nt * 16 + m] = (f16)aq[nt][r];

      f32x4 ak[4] = {{0,0,0,0},{0,0,0,0},{0,0,0,0},{0,0,0,0}};
      mm16x64h(a0, a1, wl + 1 * WFRAG, lane, ak);
      #pragma unroll
      for (int nt = 0; nt < 4; ++nt)
        #pragma unroll
        for (int r = 0; r < 4; ++r)
          Kh[(m0 + q * 4 + r) * LDB + nt * 16 + m] = (f16)ak[nt][r];

      f32x4 av[4] = {{0,0,0,0},{0,0,0,0},{0,0,0,0},{0,0,0,0}};
      mm16x64h(a0, a1, wl + 2 * WFRAG, lane, av);
      #pragma unroll
      for (int nt = 0; nt < 4; ++nt)
        #pragma unroll
        for (int r = 0; r < 4; ++r)
          Vh[(m0 + q * 4 + r) * LDB + nt * 16 + m] = (f16)av[nt][r];
    }
    __syncthreads();

    // sparse masked attention; fp16 K/V, fdot2 + pk_fma, ping-pong prefetch
    {
      const int hh = wv, i = lane;
      const uint4* qp = (const uint4*)&s.Qb[i * LDB + hh * DHEAD];
      U128h q0, q1;
      q0.u = qp[0]; q1.u = qp[1];     // scale already folded into Wq

      u64 mk = s.u.mask[i];
      float sum = 0.0f;
      h2 o2[8];
      #pragma unroll
      for (int c = 0; c < 8; ++c) o2[c] = (h2){(f16)0.0f, (f16)0.0f};

      int j = (int)__builtin_ctzll(mk); mk &= mk - 1;
      const uint4* kp = (const uint4*)&s.Kh[j * LDB + hh * DHEAD];
      const uint4* vp = (const uint4*)&s.Vh[j * LDB + hh * DHEAD];
      U128h k0, k1, v0, v1;
      k0.u = kp[0]; k1.u = kp[1]; v0.u = vp[0]; v1.u = vp[1];

      for (;;) {
        if (!mk) { attn_edge(q0, q1, k0, k1, v0, v1, sum, o2); break; }
        j = (int)__builtin_ctzll(mk); mk &= mk - 1;
        const uint4* kp2 = (const uint4*)&s.Kh[j * LDB + hh * DHEAD];
        const uint4* vp2 = (const uint4*)&s.Vh[j * LDB + hh * DHEAD];
        U128h k0b, k1b, v0b, v1b;
        k0b.u = kp2[0]; k1b.u = kp2[1]; v0b.u = vp2[0]; v1b.u = vp2[1];
        attn_edge(q0, q1, k0, k1, v0, v1, sum, o2);
        if (!mk) { attn_edge(q0, q1, k0b, k1b, v0b, v1b, sum, o2); break; }
        j = (int)__builtin_ctzll(mk); mk &= mk - 1;
        kp = (const uint4*)&s.Kh[j * LDB + hh * DHEAD];
        vp = (const uint4*)&s.Vh[j * LDB + hh * DHEAD];
        k0.u = kp[0]; k1.u = kp[1]; v0.u = vp[0]; v1.u = vp[1];
        attn_edge(q0, q1, k0b, k1b, v0b, v1b, sum, o2);
      }

      const float rinv = 1.0f / sum;
      const f16 rh = (f16)rinv;
      const h2 r2 = {rh, rh};
      U128h w0, w1;
      #pragma unroll
      for (int c = 0; c < 4; ++c) w0.v2[c] = o2[c] * r2;
      #pragma unroll
      for (int c = 0; c < 4; ++c) w1.v2[c] = o2[c + 4] * r2;
      uint4* op = (uint4*)&s.Qb[i * LDB + hh * DHEAD];
      op[0] = w0.u; op[1] = w1.u;     // fp16 out, directly MFMA-A-consumable
    }
    __syncthreads();

    // u = h + o @ Wo + bo (fp32 regs), LN (regs + shfl), h -> hr (+Hb fp16)
    {
      U128h a0, a1;
      const u16* ar = &s.Qb[(m0 + m) * LDB + q * 8];
      a0.u = *(const uint4*)ar;
      a1.u = *(const uint4*)(ar + 32);
      f32x4 ao[4] = {{0,0,0,0},{0,0,0,0},{0,0,0,0},{0,0,0,0}};
      mm16x64h(a0, a1, wl + 3 * WFRAG, lane, ao);

      float uu[4][4];
      #pragma unroll
      for (int nt = 0; nt < 4; ++nt) {
        const float bn = bo[l * HD + nt * 16 + m];
        #pragma unroll
        for (int r = 0; r < 4; ++r)
          uu[nt][r] = hr[nt][r] + ao[nt][r] + bn;
      }
      float s1[4], s2[4];
      #pragma unroll
      for (int r = 0; r < 4; ++r) {
        s1[r] = ((uu[0][r] + uu[1][r]) + (uu[2][r] + uu[3][r]));
        s2[r] = ((uu[0][r] * uu[0][r] + uu[1][r] * uu[1][r]) +
                 (uu[2][r] * uu[2][r] + uu[3][r] * uu[3][r]));
      }
      #pragma unroll
      for (int d = 1; d < 16; d <<= 1) {
        #pragma unroll
        for (int r = 0; r < 4; ++r) {
          s1[r] += __shfl_xor(s1[r], d, 64);
          s2[r] += __shfl_xor(s2[r], d, 64);
        }
      }
      float mu[4], rs[4];
      #pragma unroll
      for (int r = 0; r < 4; ++r) {
        mu[r] = s1[r] * (1.0f / 64.0f);
        const float var = s2[r] * (1.0f / 64.0f) - mu[r] * mu[r];
        rs[r] = rsqrtf(var + LN_EPS);
      }
      const bool wb = (l + 1 < NLAYERS);
      #pragma unroll
      for (int nt = 0; nt < 4; ++nt) {
        const float gv = ln_g[l * HD + nt * 16 + m];
        const float bv = ln_b[l * HD + nt * 16 + m];
        #pragma unroll
        for (int r = 0; r < 4; ++r) {
          hr[nt][r] = (uu[nt][r] - mu[r]) * rs[r] * gv + bv;
          if (wb) Hh[(m0 + q * 4 + r) * LDB + nt * 16 + m] = (f16)hr[nt][r];
        }
      }
    }
    __syncthreads();
  }

  // ---------------- head: pool (registers + LDS atomics) -> MLP
  if (t < HD) s.u.hp.pool[t] = 0.0f;
  __syncthreads();
  {
    float cs[4];
    #pragma unroll
    for (int nt = 0; nt < 4; ++nt) {
      cs[nt] = ((hr[nt][0] + hr[nt][1]) + (hr[nt][2] + hr[nt][3])) * (1.0f / 64.0f);
      cs[nt] += __shfl_xor(cs[nt], 16, 64);
      cs[nt] += __shfl_xor(cs[nt], 32, 64);
    }
    if (lane < 16) {
      #pragma unroll
      for (int nt = 0; nt < 4; ++nt)
        atomicAdd(&s.u.hp.pool[nt * 16 + lane], cs[nt]);
    }
  }
  __syncthreads();
  if (t < HD) {
    float acc = bp1[t];
    #pragma unroll 8
    for (int k = 0; k < HD; ++k) acc = fmaf(s.u.hp.pool[k], Wp1[k * HD + t], acc);
    s.u.hp.y1[t] = fmaxf(acc, 0.0f);
  }
  __syncthreads();
  if (t < ODIM) {
    float acc = bp2[t];
    #pragma unroll 8
    for (int c = 0; c < HD; ++c) acc = fmaf(s.u.hp.y1[c], Wp2[c * ODIM + t], acc);
    out[eg * ODIM + t] = acc;
  }
}

extern "C" void kernel_launch(void* const* d_in, const int* in_sizes, int n_in,
                              void* d_out, int out_size, void* d_ws, size_t ws_size,
                              hipStream_t stream) {
  const float* x    = (const float*)d_in[0];
  const int*   adj  = (const int*)d_in[1];
  const float* W_in = (const float*)d_in[2];
  const float* b_in = (const float*)d_in[3];
  const float* Wq   = (const float*)d_in[4];
  const float* Wk   = (const float*)d_in[5];
  const float* Wv   = (const float*)d_in[6];
  const float* Wo   = (const float*)d_in[7];
  const float* bo   = (const float*)d_in[8];
  const float* lng  = (const float*)d_in[9];
  const float* lnb  = (const float*)d_in[10];
  const float* Wp1  = (const float*)d_in[11];
  const float* bp1  = (const float*)d_in[12];
  const float* Wp2  = (const float*)d_in[13];
  const float* bp2  = (const float*)d_in[14];
  float* outp = (float*)d_out;
  u16*   wsW  = (u16*)d_ws;                      // 12 * 4096 u16 = 98304 B
  u64*   wsM  = (u64*)((char*)d_ws + NW * WFRAG * sizeof(u16));  // + 512 B

  hipLaunchKernelGGL(prep_pack, dim3(NW + 1), dim3(256), 0, stream,
                     Wq, Wk, Wv, Wo, adj, wsW, wsM);
  hipLaunchKernelGGL(gnn_fused, dim3(BTOT), dim3(NTH), 0, stream,
                     x, W_in, b_in, wsW, wsM, bo, lng, lnb,
                     Wp1, bp1, Wp2, bp2, outp);
}

// Round 7
// 290.603 us; speedup vs baseline: 1.3303x; 1.1083x over previous
//
#include <hip/hip_runtime.h>
#include <stdint.h>

// Problem constants
#define NB       64
#define FIN      12
#define HD       64
#define NHEADS   4
#define DHEAD    16
#define NLAYERS  3
#define ODIM     128
#define LN_EPS   1e-5f
#define BTOT     8192

#define LDB      72    // u16 stride for fp16 LDS tiles (144 B rows, 16B-aligned)
#define NTH      256
#define NW       (NLAYERS * 4)
#define WFRAG    4096  // u16 per packed weight
#define WIN_U16  2048  // packed W_in^T (zero-padded K=32): 4 mt * 64 lanes * 8

typedef unsigned int       u32;
typedef unsigned short     u16;
typedef unsigned long long u64;
typedef _Float16           f16;

typedef f16   f16x8 __attribute__((ext_vector_type(8)));
typedef f16   h2    __attribute__((ext_vector_type(2)));
typedef float f32x4 __attribute__((ext_vector_type(4)));
union U128h { uint4 u; f16x8 v8; h2 v2[4]; };

#if __has_builtin(__builtin_amdgcn_exp2f)
  __device__ __forceinline__ float e2(float x) { return __builtin_amdgcn_exp2f(x); }
#else
  __device__ __forceinline__ float e2(float x) { return exp2f(x); }
#endif

__device__ __forceinline__ float fdot2h(h2 a, h2 b, float c) {
#if __has_builtin(__builtin_amdgcn_fdot2)
  return __builtin_amdgcn_fdot2(a, b, c, false);
#else
  return c + (float)a[0] * (float)b[0] + (float)a[1] * (float)b[1];
#endif
}

// pack two fp32 -> 2 fp16 (RNE casts; compiler emits cvt+cvt+pack)
__device__ __forceinline__ u32 packh2(float a, float b) {
  h2 p = {(f16)a, (f16)b};
  return *(u32*)&p;
}
// write 4 fp16 (one C-fragment column run) as b64
__device__ __forceinline__ void wb4(u16* __restrict__ dst, f32x4 a) {
  *(uint2*)dst = make_uint2(packh2(a[0], a[1]), packh2(a[2], a[3]));
}

struct __align__(16) Smem {
  u16 Kh[NB * LDB];   // 9216  k fp16
  u16 Vh[NB * LDB];   // 9216  v fp16
  u16 Hb[NB * LDB];   // 9216  h fp16 (MFMA B-source, [node][feat])
  u16 Qb[NB * LDB];   // 9216  q fp16; x-staging [node][32] in phase 0; attn out o
  union {             //  512  disjoint lifetimes
    u64 mask[NB];
    struct { float pool[HD]; float y1[HD]; } hp;
  } u;
};                    // 37376 B -> 4 blocks/CU

// ---------------- prep: pack weights (fragment order, bytes unchanged from r6),
// W_in^T zero-padded to K=32, adjacency masks.
extern "C" __global__ void __launch_bounds__(256)
prep_pack(const float* __restrict__ Wq, const float* __restrict__ Wk,
          const float* __restrict__ Wv, const float* __restrict__ Wo,
          const float* __restrict__ W_in, const int* __restrict__ adj,
          u16* __restrict__ wsW) {
  const int w = blockIdx.x;
  if (w < NW) {
    const int l = w >> 2, ty = w & 3;
    const float* src = (ty == 0 ? Wq : ty == 1 ? Wk : ty == 2 ? Wv : Wo) + l * HD * HD;
    const float sc = (ty == 0) ? (0.25f * 1.44269504f) : 1.0f;  // fold softmax*log2e into Wq
    u16* dst = wsW + w * WFRAG;
    for (int f = threadIdx.x; f < 512; f += 256) {
      const int lane = f & 63, kh = (f >> 6) & 1, nt = f >> 7;
      const int n  = nt * 16 + (lane & 15);
      const int k0 = kh * 32 + ((lane >> 4) & 3) * 8;
      u16 tmp[8];
      #pragma unroll
      for (int j = 0; j < 8; ++j) {
        f16 hv = (f16)(src[(k0 + j) * HD + n] * sc);
        tmp[j] = *(u16*)&hv;
      }
      *(uint4*)(dst + f * 8) = *(const uint4*)tmp;
    }
  } else if (w == NW) {
    // W_in^T as A-fragments, K zero-padded 12->32. elem j: A[m=mt*16+(lane&15)][k=q*8+j]
    const int t = threadIdx.x;           // t = mt*64 + lane
    const int mt = t >> 6, lane = t & 63;
    const int mm = lane & 15, qq = (lane >> 4) & 3;
    u16 tmp[8];
    #pragma unroll
    for (int j = 0; j < 8; ++j) {
      const int k = qq * 8 + j;
      f16 hv = (k < FIN) ? (f16)W_in[k * HD + mt * 16 + mm] : (f16)0.0f;
      tmp[j] = *(u16*)&hv;
    }
    *(uint4*)(wsW + NW * WFRAG + t * 8) = *(const uint4*)tmp;
  } else {
    const int t = threadIdx.x;
    u64* wsM = (u64*)(wsW + NW * WFRAG + WIN_U16);
    if (t < NB) {
      u64 mm = 0ull;
      for (int j = 0; j < NB; ++j)
        if (adj[t * NB + j] != 0) mm |= (1ull << j);
      wsM[t] = mm;
    }
  }
}

// Transposed GEMM: C^T = W^T(64x64) @ H^T. A-frags = packed weights (global),
// B-frags = h rows from LDS (b0: k0..31, b1: k32..63).
// C^T layout: row feat = mt*16 + q*4 + r, col node = wv*16 + (lane&15).
__device__ __forceinline__ void mmT(const u16* __restrict__ wf, U128h b0, U128h b1,
                                    int lane, f32x4 acc[4]) {
  #pragma unroll
  for (int mt = 0; mt < 4; ++mt) {
    U128h a0, a1;
    a0.u = *(const uint4*)(wf + ((mt * 2 + 0) * 64 + lane) * 8);
    a1.u = *(const uint4*)(wf + ((mt * 2 + 1) * 64 + lane) * 8);
    acc[mt] = __builtin_amdgcn_mfma_f32_16x16x32_f16(a0.v8, b0.v8, acc[mt], 0, 0, 0);
    acc[mt] = __builtin_amdgcn_mfma_f32_16x16x32_f16(a1.v8, b1.v8, acc[mt], 0, 0, 0);
  }
}

// one attention edge: s = q.k (fdot2 chains), p = exp2(s), o += p*v
__device__ __forceinline__ void attn_edge(const U128h& q0, const U128h& q1,
                                          U128h k0, U128h k1, U128h v0, U128h v1,
                                          float& sum, h2* __restrict__ o) {
  float d0 = fdot2h(q0.v2[0], k0.v2[0], 0.0f);
  d0 = fdot2h(q0.v2[1], k0.v2[1], d0);
  d0 = fdot2h(q0.v2[2], k0.v2[2], d0);
  d0 = fdot2h(q0.v2[3], k0.v2[3], d0);
  float d1 = fdot2h(q1.v2[0], k1.v2[0], 0.0f);
  d1 = fdot2h(q1.v2[1], k1.v2[1], d1);
  d1 = fdot2h(q1.v2[2], k1.v2[2], d1);
  d1 = fdot2h(q1.v2[3], k1.v2[3], d1);
  const float p = e2(d0 + d1);
  sum += p;
  const f16 ph = (f16)p;
  const h2 p2 = {ph, ph};
  o[0] += p2 * v0.v2[0]; o[1] += p2 * v0.v2[1];
  o[2] += p2 * v0.v2[2]; o[3] += p2 * v0.v2[3];
  o[4] += p2 * v1.v2[0]; o[5] += p2 * v1.v2[1];
  o[6] += p2 * v1.v2[2]; o[7] += p2 * v1.v2[3];
}

extern "C" __global__ void __launch_bounds__(NTH, 4)
gnn_fused(const float* __restrict__ x, const float* __restrict__ b_in,
          const u16* __restrict__ wsW, const float* __restrict__ bo,
          const float* __restrict__ ln_g, const float* __restrict__ ln_b,
          const float* __restrict__ Wp1, const float* __restrict__ bp1,
          const float* __restrict__ Wp2, const float* __restrict__ bp2,
          float* __restrict__ out) {
  __shared__ Smem s;
  const int t    = threadIdx.x;
  const int lane = t & 63;
  const int wv   = t >> 6;
  const int eg   = (int)blockIdx.x;
  const int m    = lane & 15, q = lane >> 4;
  const int node = wv * 16 + m;          // this lane's node (transposed layout)

  const u16* wsWin = wsW + NW * WFRAG;
  const u64* wsM   = (const u64*)(wsWin + WIN_U16);

  // ---------------- phase 0: zero x-staging (Qb), copy masks
  ((uint4*)s.Qb)[t] = make_uint4(0u, 0u, 0u, 0u);   // 256*16B = 4096B = [node][32] f16
  if (t < NB) s.u.mask[t] = wsM[t];
  __syncthreads();

  // x -> f16 staging [node][32] (k>=12 stays zero)
  if (t < (NB * FIN) / 4) {
    const int nd = t / 3, pos = (t % 3) * 4;
    const float4 v4 = *(const float4*)(x + eg * NB * FIN + t * 4);
    *(uint2*)&s.Qb[nd * 32 + pos] = make_uint2(packh2(v4.x, v4.y), packh2(v4.z, v4.w));
  }
  __syncthreads();

  // ---------------- input projection via MFMA: h^T = W_in^T @ x^T (K=32 padded)
  float hr[4][4];   // hr[mt][r]: h[node][feat = mt*16 + q*4 + r]
  {
    U128h xb;
    xb.u = *(const uint4*)&s.Qb[node * 32 + q * 8];
    #pragma unroll
    for (int mt = 0; mt < 4; ++mt) {
      U128h a0;
      a0.u = *(const uint4*)(wsWin + (mt * 64 + lane) * 8);
      f32x4 acc = {0.f, 0.f, 0.f, 0.f};
      acc = __builtin_amdgcn_mfma_f32_16x16x32_f16(a0.v8, xb.v8, acc, 0, 0, 0);
      const f32x4 b4 = *(const f32x4*)&b_in[mt * 16 + q * 4];
      #pragma unroll
      for (int r = 0; r < 4; ++r) hr[mt][r] = acc[r] + b4[r];
    }
  }
  __syncthreads();   // staging dead; write Hb
  #pragma unroll
  for (int mt = 0; mt < 4; ++mt) {
    f32x4 hv = {hr[mt][0], hr[mt][1], hr[mt][2], hr[mt][3]};
    wb4(&s.Hb[node * LDB + mt * 16 + q * 4], hv);
  }
  __syncthreads();

  // ---------------- transformer layers
  for (int l = 0; l < NLAYERS; ++l) {
    const u16* wl = wsW + (l * 4) * WFRAG;

    // fused q/k/v projections (transposed; shared B-fragments = h rows)
    {
      U128h b0, b1;
      const u16* hbp = &s.Hb[node * LDB + q * 8];
      b0.u = *(const uint4*)hbp;
      b1.u = *(const uint4*)(hbp + 32);

      f32x4 aq[4] = {{0,0,0,0},{0,0,0,0},{0,0,0,0},{0,0,0,0}};
      mmT(wl + 0 * WFRAG, b0, b1, lane, aq);
      #pragma unroll
      for (int mt = 0; mt < 4; ++mt)
        wb4(&s.Qb[node * LDB + mt * 16 + q * 4], aq[mt]);

      f32x4 ak[4] = {{0,0,0,0},{0,0,0,0},{0,0,0,0},{0,0,0,0}};
      mmT(wl + 1 * WFRAG, b0, b1, lane, ak);
      #pragma unroll
      for (int mt = 0; mt < 4; ++mt)
        wb4(&s.Kh[node * LDB + mt * 16 + q * 4], ak[mt]);

      f32x4 av[4] = {{0,0,0,0},{0,0,0,0},{0,0,0,0},{0,0,0,0}};
      mmT(wl + 2 * WFRAG, b0, b1, lane, av);
      #pragma unroll
      for (int mt = 0; mt < 4; ++mt)
        wb4(&s.Vh[node * LDB + mt * 16 + q * 4], av[mt]);
    }
    __syncthreads();

    // sparse masked attention (unchanged; [node][feat] tiles)
    {
      const int hh = wv, i = lane;
      const uint4* qp = (const uint4*)&s.Qb[i * LDB + hh * DHEAD];
      U128h q0, q1;
      q0.u = qp[0]; q1.u = qp[1];

      u64 mk = s.u.mask[i];
      float sum = 0.0f;
      h2 o2[8];
      #pragma unroll
      for (int c = 0; c < 8; ++c) o2[c] = (h2){(f16)0.0f, (f16)0.0f};

      int j = (int)__builtin_ctzll(mk); mk &= mk - 1;
      const uint4* kp = (const uint4*)&s.Kh[j * LDB + hh * DHEAD];
      const uint4* vp = (const uint4*)&s.Vh[j * LDB + hh * DHEAD];
      U128h k0, k1, v0, v1;
      k0.u = kp[0]; k1.u = kp[1]; v0.u = vp[0]; v1.u = vp[1];

      for (;;) {
        if (!mk) { attn_edge(q0, q1, k0, k1, v0, v1, sum, o2); break; }
        j = (int)__builtin_ctzll(mk); mk &= mk - 1;
        const uint4* kp2 = (const uint4*)&s.Kh[j * LDB + hh * DHEAD];
        const uint4* vp2 = (const uint4*)&s.Vh[j * LDB + hh * DHEAD];
        U128h k0b, k1b, v0b, v1b;
        k0b.u = kp2[0]; k1b.u = kp2[1]; v0b.u = vp2[0]; v1b.u = vp2[1];
        attn_edge(q0, q1, k0, k1, v0, v1, sum, o2);
        if (!mk) { attn_edge(q0, q1, k0b, k1b, v0b, v1b, sum, o2); break; }
        j = (int)__builtin_ctzll(mk); mk &= mk - 1;
        kp = (const uint4*)&s.Kh[j * LDB + hh * DHEAD];
        vp = (const uint4*)&s.Vh[j * LDB + hh * DHEAD];
        k0.u = kp[0]; k1.u = kp[1]; v0.u = vp[0]; v1.u = vp[1];
        attn_edge(q0, q1, k0b, k1b, v0b, v1b, sum, o2);
      }

      const float rinv = 1.0f / sum;
      const f16 rh = (f16)rinv;
      const h2 r2 = {rh, rh};
      U128h w0, w1;
      #pragma unroll
      for (int c = 0; c < 4; ++c) w0.v2[c] = o2[c] * r2;
      #pragma unroll
      for (int c = 0; c < 4; ++c) w1.v2[c] = o2[c + 4] * r2;
      uint4* op = (uint4*)&s.Qb[i * LDB + hh * DHEAD];
      op[0] = w0.u; op[1] = w1.u;
    }
    __syncthreads();

    // u = h + o @ Wo + bo (transposed GEMM), LN over q-lanes (2 shfl steps)
    {
      U128h b0, b1;
      const u16* obp = &s.Qb[node * LDB + q * 8];
      b0.u = *(const uint4*)obp;
      b1.u = *(const uint4*)(obp + 32);
      f32x4 ao[4] = {{0,0,0,0},{0,0,0,0},{0,0,0,0},{0,0,0,0}};
      mmT(wl + 3 * WFRAG, b0, b1, lane, ao);

      float uu[4][4];
      float s1 = 0.0f, s2 = 0.0f;
      #pragma unroll
      for (int mt = 0; mt < 4; ++mt) {
        const f32x4 bo4 = *(const f32x4*)&bo[l * HD + mt * 16 + q * 4];
        #pragma unroll
        for (int r = 0; r < 4; ++r) {
          const float v = hr[mt][r] + ao[mt][r] + bo4[r];
          uu[mt][r] = v;
          s1 += v;
          s2 += v * v;
        }
      }
      s1 += __shfl_xor(s1, 16, 64); s1 += __shfl_xor(s1, 32, 64);
      s2 += __shfl_xor(s2, 16, 64); s2 += __shfl_xor(s2, 32, 64);
      const float mu  = s1 * (1.0f / 64.0f);
      const float var = s2 * (1.0f / 64.0f) - mu * mu;
      const float rs  = rsqrtf(var + LN_EPS);
      const bool wb = (l + 1 < NLAYERS);
      #pragma unroll
      for (int mt = 0; mt < 4; ++mt) {
        const f32x4 g4 = *(const f32x4*)&ln_g[l * HD + mt * 16 + q * 4];
        const f32x4 b4 = *(const f32x4*)&ln_b[l * HD + mt * 16 + q * 4];
        #pragma unroll
        for (int r = 0; r < 4; ++r)
          hr[mt][r] = (uu[mt][r] - mu) * rs * g4[r] + b4[r];
        if (wb) {
          f32x4 hv = {hr[mt][0], hr[mt][1], hr[mt][2], hr[mt][3]};
          wb4(&s.Hb[node * LDB + mt * 16 + q * 4], hv);
        }
      }
    }
    __syncthreads();
  }

  // ---------------- head: butterfly over node-lanes (m), atomic pool, MLP
  if (t < HD) s.u.hp.pool[t] = 0.0f;
  __syncthreads();
  {
    #pragma unroll
    for (int mt = 0; mt < 4; ++mt)
      #pragma unroll
      for (int r = 0; r < 4; ++r) {
        float v = hr[mt][r];
        v += __shfl_xor(v, 1, 64); v += __shfl_xor(v, 2, 64);
        v += __shfl_xor(v, 4, 64); v += __shfl_xor(v, 8, 64);
        hr[mt][r] = v;
      }
    if (m == 0) {
      #pragma unroll
      for (int mt = 0; mt < 4; ++mt)
        #pragma unroll
        for (int r = 0; r < 4; ++r)
          atomicAdd(&s.u.hp.pool[mt * 16 + q * 4 + r], hr[mt][r] * (1.0f / 64.0f));
    }
  }
  __syncthreads();
  if (t < HD) {
    float acc = bp1[t];
    #pragma unroll 8
    for (int k = 0; k < HD; ++k) acc = fmaf(s.u.hp.pool[k], Wp1[k * HD + t], acc);
    s.u.hp.y1[t] = fmaxf(acc, 0.0f);
  }
  __syncthreads();
  if (t < ODIM) {
    float acc = bp2[t];
    #pragma unroll 8
    for (int c = 0; c < HD; ++c) acc = fmaf(s.u.hp.y1[c], Wp2[c * ODIM + t], acc);
    out[eg * ODIM + t] = acc;
  }
}

extern "C" void kernel_launch(void* const* d_in, const int* in_sizes, int n_in,
                              void* d_out, int out_size, void* d_ws, size_t ws_size,
                              hipStream_t stream) {
  const float* x    = (const float*)d_in[0];
  const int*   adj  = (const int*)d_in[1];
  const float* W_in = (const float*)d_in[2];
  const float* b_in = (const float*)d_in[3];
  const float* Wq   = (const float*)d_in[4];
  const float* Wk   = (const float*)d_in[5];
  const float* Wv   = (const float*)d_in[6];
  const float* Wo   = (const float*)d_in[7];
  const float* bo   = (const float*)d_in[8];
  const float* lng  = (const float*)d_in[9];
  const float* lnb  = (const float*)d_in[10];
  const float* Wp1  = (const float*)d_in[11];
  const float* bp1  = (const float*)d_in[12];
  const float* Wp2  = (const float*)d_in[13];
  const float* bp2  = (const float*)d_in[14];
  float* outp = (float*)d_out;
  u16*   wsW  = (u16*)d_ws;   // 12*4096 + 2048 u16 + 512 B masks = ~103 KB

  hipLaunchKernelGGL(prep_pack, dim3(NW + 2), dim3(256), 0, stream,
                     Wq, Wk, Wv, Wo, W_in, adj, wsW);
  hipLaunchKernelGGL(gnn_fused, dim3(BTOT), dim3(NTH), 0, stream,
                     x, b_in, wsW, bo, lng, lnb, Wp1, bp1, Wp2, bp2, outp);
}